// Round 5
// baseline (445.264 us; speedup 1.0000x reference)
//
#include <hip/hip_runtime.h>
#include <math.h>

// CentroidInstanceLoss: N=2M points, D=16, B=8 subbatches, M=32 labels.
// out = (L_pull + L_push)/B  (single fp32 scalar)
//
// R5: register-batched loads. R4 lesson: VGPR=28 -> one iteration's loads in
// flight -> latency-serialized (~1 TB/s). Each thread now owns 4 points and
// issues all 24 loads in one clause before computing (18.4 KB/wave in flight).

#define DD 16
#define MM 32
#define BBATCH 8
#define SEGS 256          // B*M
#define DELTA_V 0.5f
#define DELTA_D 1.5f
#define NEPS 1e-8f

#define NBLK 2048
#define NTHR 256
#define PPT 4             // points per thread
#define CHUNK (NTHR * PPT)  // 1024 points per block

// ws layout (floats):
//   [0,4096)        seg_sum   [seg][d]    (HW fp atomics)
//   [4096,4352)     seg_cnt   [seg]
//   [4352,8448)     mus       [seg][d]  (seg-major)
//   [8448,8704)     invw      [seg]   = 1/(M*count)
//   [8704]          push_acc
//   [8720,8720+NBLK) pull_part
#define WS_ZERO_FLOATS 4352

__device__ __forceinline__ void lds_fadd(float* p, float v) {
    __hip_atomic_fetch_add(p, v, __ATOMIC_RELAXED, __HIP_MEMORY_SCOPE_WORKGROUP);
}

__device__ __forceinline__ float block_reduce_sum(float v) {
    #pragma unroll
    for (int o = 32; o > 0; o >>= 1) v += __shfl_down(v, o, 64);
    __shared__ float red[4];
    int wid  = threadIdx.x >> 6;
    int lane = threadIdx.x & 63;
    if (lane == 0) red[wid] = v;
    __syncthreads();
    v = (threadIdx.x < (NTHR >> 6)) ? red[threadIdx.x] : 0.0f;
    if (wid == 0) {
        #pragma unroll
        for (int o = 32; o > 0; o >>= 1) v += __shfl_down(v, o, 64);
    }
    return v;  // valid on thread 0
}

__global__ void __launch_bounds__(NTHR, 4)
k_segsum(const float4* __restrict__ o4,
         const int* __restrict__ labels,
         const int* __restrict__ sub,
         float* __restrict__ seg_sum,
         float* __restrict__ seg_cnt,
         int n) {
    __shared__ float lsT[(DD + 1) * SEGS];  // planes [d][seg]; plane 16 = count
    for (int i = threadIdx.x; i < (DD + 1) * SEGS; i += NTHR) lsT[i] = 0.0f;
    __syncthreads();

    const int base = blockIdx.x * CHUNK + threadIdx.x;

    // ---- load phase: all PPT points' data in one clause (branch-free) ----
    float4 x[PPT][4];
    int    sg[PPT];
    #pragma unroll
    for (int k = 0; k < PPT; ++k) {
        int p  = base + k * NTHR;
        int pc = (p < n) ? p : (n - 1);       // clamp; masked in compute
        x[k][0] = o4[4 * pc + 0];
        x[k][1] = o4[4 * pc + 1];
        x[k][2] = o4[4 * pc + 2];
        x[k][3] = o4[4 * pc + 3];
        sg[k]   = sub[pc] * MM + labels[pc];
    }

    // ---- compute phase: register-resident per-seg accumulation ----
    float4 a0 = {0,0,0,0}, a1 = {0,0,0,0}, a2 = {0,0,0,0}, a3 = {0,0,0,0};
    float cnt = 0.0f;
    int cur = -1;
    #pragma unroll
    for (int k = 0; k < PPT; ++k) {
        int p = base + k * NTHR;
        if (p >= n) break;
        float4 a = x[k][0], b = x[k][1], c = x[k][2], e = x[k][3];
        float ss = a.x*a.x + a.y*a.y + a.z*a.z + a.w*a.w
                 + b.x*b.x + b.y*b.y + b.z*b.z + b.w*b.w
                 + c.x*c.x + c.y*c.y + c.z*c.z + c.w*c.w
                 + e.x*e.x + e.y*e.y + e.z*e.z + e.w*e.w;
        float rn = 1.0f / (sqrtf(ss) + NEPS);
        int seg = sg[k];
        if (seg != cur) {              // rare (once/thread for canonical input)
            if (cur >= 0) {
                lds_fadd(&lsT[ 0*SEGS + cur], a0.x); lds_fadd(&lsT[ 1*SEGS + cur], a0.y);
                lds_fadd(&lsT[ 2*SEGS + cur], a0.z); lds_fadd(&lsT[ 3*SEGS + cur], a0.w);
                lds_fadd(&lsT[ 4*SEGS + cur], a1.x); lds_fadd(&lsT[ 5*SEGS + cur], a1.y);
                lds_fadd(&lsT[ 6*SEGS + cur], a1.z); lds_fadd(&lsT[ 7*SEGS + cur], a1.w);
                lds_fadd(&lsT[ 8*SEGS + cur], a2.x); lds_fadd(&lsT[ 9*SEGS + cur], a2.y);
                lds_fadd(&lsT[10*SEGS + cur], a2.z); lds_fadd(&lsT[11*SEGS + cur], a2.w);
                lds_fadd(&lsT[12*SEGS + cur], a3.x); lds_fadd(&lsT[13*SEGS + cur], a3.y);
                lds_fadd(&lsT[14*SEGS + cur], a3.z); lds_fadd(&lsT[15*SEGS + cur], a3.w);
                lds_fadd(&lsT[16*SEGS + cur], cnt);
            }
            a0 = a1 = a2 = a3 = (float4){0,0,0,0};
            cnt = 0.0f;
            cur = seg;
        }
        a0.x += a.x * rn; a0.y += a.y * rn; a0.z += a.z * rn; a0.w += a.w * rn;
        a1.x += b.x * rn; a1.y += b.y * rn; a1.z += b.z * rn; a1.w += b.w * rn;
        a2.x += c.x * rn; a2.y += c.y * rn; a2.z += c.z * rn; a2.w += c.w * rn;
        a3.x += e.x * rn; a3.y += e.y * rn; a3.z += e.z * rn; a3.w += e.w * rn;
        cnt += 1.0f;
    }
    if (cur >= 0) {
        lds_fadd(&lsT[ 0*SEGS + cur], a0.x); lds_fadd(&lsT[ 1*SEGS + cur], a0.y);
        lds_fadd(&lsT[ 2*SEGS + cur], a0.z); lds_fadd(&lsT[ 3*SEGS + cur], a0.w);
        lds_fadd(&lsT[ 4*SEGS + cur], a1.x); lds_fadd(&lsT[ 5*SEGS + cur], a1.y);
        lds_fadd(&lsT[ 6*SEGS + cur], a1.z); lds_fadd(&lsT[ 7*SEGS + cur], a1.w);
        lds_fadd(&lsT[ 8*SEGS + cur], a2.x); lds_fadd(&lsT[ 9*SEGS + cur], a2.y);
        lds_fadd(&lsT[10*SEGS + cur], a2.z); lds_fadd(&lsT[11*SEGS + cur], a2.w);
        lds_fadd(&lsT[12*SEGS + cur], a3.x); lds_fadd(&lsT[13*SEGS + cur], a3.y);
        lds_fadd(&lsT[14*SEGS + cur], a3.z); lds_fadd(&lsT[15*SEGS + cur], a3.w);
        lds_fadd(&lsT[16*SEGS + cur], cnt);
    }
    __syncthreads();
    // global flush: only segments this block actually touched (count != 0)
    for (int s = threadIdx.x; s < SEGS; s += NTHR) {
        float c = lsT[DD * SEGS + s];
        if (c != 0.0f) {
            #pragma unroll
            for (int d = 0; d < DD; ++d)
                unsafeAtomicAdd(&seg_sum[s * DD + d], lsT[d * SEGS + s]);
            unsafeAtomicAdd(&seg_cnt[s], c);
        }
    }
}

__global__ void k_finalize_push(float* __restrict__ ws) {
    const float* seg_sum = ws;
    const float* seg_cnt = ws + 4096;
    float* mus  = ws + 4352;
    float* invw = ws + 8448;
    float* push = ws + 8704;

    __shared__ float muT[DD * SEGS];
    int t = threadIdx.x;  // 256 threads == one per segment
    float cnt = seg_cnt[t];
    float ic  = (cnt > 0.0f) ? 1.0f / cnt : 0.0f;
    #pragma unroll
    for (int d = 0; d < DD; ++d) {
        float m = seg_sum[t * DD + d] * ic;
        mus[t * DD + d]   = m;
        muT[d * SEGS + t] = m;
    }
    invw[t] = (cnt > 0.0f) ? 1.0f / ((float)MM * cnt) : 0.0f;
    __syncthreads();

    int b = t >> 5, m1 = t & 31;
    float acc = 0.0f;
    for (int m2 = 0; m2 < MM; ++m2) {
        float pd = 0.0f;
        #pragma unroll
        for (int d = 0; d < DD; ++d)
            pd += fabsf(muT[d * SEGS + b * MM + m1] - muT[d * SEGS + b * MM + m2]);
        float h = 2.0f * DELTA_D - pd;
        if (m2 != m1 && h > 0.0f) acc += h * h;
    }
    float tot = block_reduce_sum(acc);
    if (t == 0) push[0] = tot / (float)(MM * (MM - 1));
}

__global__ void __launch_bounds__(NTHR, 4)
k_pull(const float4* __restrict__ o4,
       const int* __restrict__ labels,
       const int* __restrict__ sub,
       const float* __restrict__ mus,
       const float* __restrict__ invw,
       float* __restrict__ pull_part,
       int n) {
    __shared__ float muL[DD * SEGS];  // seg-major (matches ws mus layout)
    __shared__ float siw[SEGS];
    for (int i = threadIdx.x; i < DD * SEGS; i += NTHR) muL[i] = mus[i];
    for (int i = threadIdx.x; i < SEGS; i += NTHR) siw[i] = invw[i];
    __syncthreads();

    const int base = blockIdx.x * CHUNK + threadIdx.x;

    float4 x[PPT][4];
    int    sg[PPT];
    #pragma unroll
    for (int k = 0; k < PPT; ++k) {
        int p  = base + k * NTHR;
        int pc = (p < n) ? p : (n - 1);
        x[k][0] = o4[4 * pc + 0];
        x[k][1] = o4[4 * pc + 1];
        x[k][2] = o4[4 * pc + 2];
        x[k][3] = o4[4 * pc + 3];
        sg[k]   = sub[pc] * MM + labels[pc];
    }

    float4 m0, m1, m2, m3;
    float iw = 0.0f;
    int cur = -1;
    float acc = 0.0f;
    #pragma unroll
    for (int k = 0; k < PPT; ++k) {
        int p = base + k * NTHR;
        if (p >= n) break;
        float4 a = x[k][0], b = x[k][1], c = x[k][2], e = x[k][3];
        int seg = sg[k];
        if (seg != cur) {              // once per thread for canonical input
            cur = seg;
            m0 = *(const float4*)&muL[seg * DD +  0];
            m1 = *(const float4*)&muL[seg * DD +  4];
            m2 = *(const float4*)&muL[seg * DD +  8];
            m3 = *(const float4*)&muL[seg * DD + 12];
            iw = siw[seg];
        }
        float ss = a.x*a.x + a.y*a.y + a.z*a.z + a.w*a.w
                 + b.x*b.x + b.y*b.y + b.z*b.z + b.w*b.w
                 + c.x*c.x + c.y*c.y + c.z*c.z + c.w*c.w
                 + e.x*e.x + e.y*e.y + e.z*e.z + e.w*e.w;
        float rn = 1.0f / (sqrtf(ss) + NEPS);
        float dist;
        dist  = fabsf(m0.x - a.x * rn) + fabsf(m0.y - a.y * rn)
              + fabsf(m0.z - a.z * rn) + fabsf(m0.w - a.w * rn);
        dist += fabsf(m1.x - b.x * rn) + fabsf(m1.y - b.y * rn)
              + fabsf(m1.z - b.z * rn) + fabsf(m1.w - b.w * rn);
        dist += fabsf(m2.x - c.x * rn) + fabsf(m2.y - c.y * rn)
              + fabsf(m2.z - c.z * rn) + fabsf(m2.w - c.w * rn);
        dist += fabsf(m3.x - e.x * rn) + fabsf(m3.y - e.y * rn)
              + fabsf(m3.z - e.z * rn) + fabsf(m3.w - e.w * rn);
        float h = dist - DELTA_V;
        if (h > 0.0f) acc = fmaf(h * h, iw, acc);
    }
    float tot = block_reduce_sum(acc);
    if (threadIdx.x == 0) pull_part[blockIdx.x] = tot;
}

__global__ void k_final(const float* __restrict__ ws, float* __restrict__ out) {
    const float* push      = ws + 8704;
    const float* pull_part = ws + 8720;
    int t = threadIdx.x;
    float v = 0.0f;
    #pragma unroll
    for (int k = 0; k < NBLK / NTHR; ++k) v += pull_part[t + k * NTHR];
    float tot = block_reduce_sum(v);
    if (t == 0) out[0] = (tot + push[0]) * (1.0f / (float)BBATCH);
}

extern "C" void kernel_launch(void* const* d_in, const int* in_sizes, int n_in,
                              void* d_out, int out_size, void* d_ws, size_t ws_size,
                              hipStream_t stream) {
    const float* outputs = (const float*)d_in[0];
    const int* labels    = (const int*)d_in[1];
    const int* sub       = (const int*)d_in[2];
    int n = in_sizes[0] / DD;

    float* ws        = (float*)d_ws;
    float* seg_sum   = ws;
    float* seg_cnt   = ws + 4096;
    float* mus       = ws + 4352;
    float* invw      = ws + 8448;
    float* pull_part = ws + 8720;

    hipMemsetAsync(d_ws, 0, WS_ZERO_FLOATS * sizeof(float), stream);

    k_segsum<<<NBLK, NTHR, 0, stream>>>((const float4*)outputs, labels, sub,
                                        seg_sum, seg_cnt, n);
    k_finalize_push<<<1, NTHR, 0, stream>>>(ws);
    k_pull<<<NBLK, NTHR, 0, stream>>>((const float4*)outputs, labels, sub,
                                      mus, invw, pull_part, n);
    k_final<<<1, NTHR, 0, stream>>>(ws, (float*)d_out);
}

// Round 7
// 329.347 us; speedup vs baseline: 1.3520x; 1.3520x over previous
//
#include <hip/hip_runtime.h>
#include <math.h>

// CentroidInstanceLoss: N=2M points, D=16, B=8 subbatches, M=32 labels.
// out = (L_pull + L_push)/B  (single fp32 scalar)
//
// R7: coalesced loads (lane i -> float4 i, 16B stride) + register-resident
// per-lane 4-dim segment accumulation, quad shfl_xor for norm/dist reductions.
// R4 lesson: per-thread-owns-point => 64B lane stride => 64 lines/instr =>
// ~1 TB/s address-rate wall. R3 lesson: don't put atomics in the hot loop.

#define DD 16
#define MM 32
#define BBATCH 8
#define SEGS 256          // B*M
#define DELTA_V 0.5f
#define DELTA_D 1.5f
#define NEPS 1e-8f

#define NBLK 1024
#define NTHR 256
#define CHUNKP 2048               // points per block (NBLK*CHUNKP == N)
#define ITERS (CHUNKP * 4 / NTHR) // 32 float4-iterations per thread

// ws layout (floats):
//   [0,4096)        seg_sum   [seg][d]    (HW fp atomics)
//   [4096,4352)     seg_cnt   [seg]
//   [4352,8448)     mus       [seg][d]  (seg-major)
//   [8448,8704)     invw      [seg]   = 1/(M*count)
//   [8704]          push_acc
//   [8720,8720+NBLK) pull_part
#define WS_ZERO_FLOATS 4352

__device__ __forceinline__ void lds_fadd(float* p, float v) {
    __hip_atomic_fetch_add(p, v, __ATOMIC_RELAXED, __HIP_MEMORY_SCOPE_WORKGROUP);
}

__device__ __forceinline__ float block_reduce_sum(float v) {
    #pragma unroll
    for (int o = 32; o > 0; o >>= 1) v += __shfl_down(v, o, 64);
    __shared__ float red[4];
    int wid  = threadIdx.x >> 6;
    int lane = threadIdx.x & 63;
    if (lane == 0) red[wid] = v;
    __syncthreads();
    v = (threadIdx.x < (NTHR >> 6)) ? red[threadIdx.x] : 0.0f;
    if (wid == 0) {
        #pragma unroll
        for (int o = 32; o > 0; o >>= 1) v += __shfl_down(v, o, 64);
    }
    return v;  // valid on thread 0
}

__global__ void __launch_bounds__(NTHR, 8)
k_segsum(const float4* __restrict__ o4,
         const int* __restrict__ labels,
         const int* __restrict__ sub,
         float* __restrict__ seg_sum,
         float* __restrict__ seg_cnt,
         int n) {
    __shared__ float lsT[(DD + 1) * SEGS];  // planes [d][seg]; plane 16 = count
    for (int i = threadIdx.x; i < (DD + 1) * SEGS; i += NTHR) lsT[i] = 0.0f;
    __syncthreads();

    const int tid = threadIdx.x;
    const int j   = tid & 3;                     // quad slot, loop-invariant
    const int n4  = 4 * n;
    const int qbase = blockIdx.x * (CHUNKP * 4) + tid;

    float4 av = {0.0f, 0.0f, 0.0f, 0.0f};
    float cnt = 0.0f;
    int cur = -1;

    #pragma unroll 4
    for (int it = 0; it < ITERS; ++it) {
        int q = qbase + it * NTHR;
        bool ok = (q < n4);                      // uniform across a quad
        int qc = ok ? q : 0;
        float4 v = o4[qc];                       // lane i -> float4 i: coalesced
        int p = qc >> 2;
        int seg = sub[p] * MM + labels[p];
        float ss = v.x*v.x + v.y*v.y + v.z*v.z + v.w*v.w;
        ss += __shfl_xor(ss, 1, 64);
        ss += __shfl_xor(ss, 2, 64);             // full ||x||^2 across the quad
        float rn = 1.0f / (sqrtf(ss) + NEPS);
        if (ok) {
            if (seg != cur) {                    // rare (invariant for canonical)
                if (cur >= 0) {
                    lds_fadd(&lsT[(4*j + 0) * SEGS + cur], av.x);
                    lds_fadd(&lsT[(4*j + 1) * SEGS + cur], av.y);
                    lds_fadd(&lsT[(4*j + 2) * SEGS + cur], av.z);
                    lds_fadd(&lsT[(4*j + 3) * SEGS + cur], av.w);
                    if (j == 0) lds_fadd(&lsT[DD * SEGS + cur], cnt);
                    av = (float4){0.0f, 0.0f, 0.0f, 0.0f};
                    cnt = 0.0f;
                }
                cur = seg;
            }
            av.x += v.x * rn; av.y += v.y * rn;
            av.z += v.z * rn; av.w += v.w * rn;
            cnt += 1.0f;
        }
    }
    if (cur >= 0) {
        lds_fadd(&lsT[(4*j + 0) * SEGS + cur], av.x);
        lds_fadd(&lsT[(4*j + 1) * SEGS + cur], av.y);
        lds_fadd(&lsT[(4*j + 2) * SEGS + cur], av.z);
        lds_fadd(&lsT[(4*j + 3) * SEGS + cur], av.w);
        if (j == 0) lds_fadd(&lsT[DD * SEGS + cur], cnt);
    }
    __syncthreads();
    // global flush: only segments this block actually touched (count != 0)
    for (int s = threadIdx.x; s < SEGS; s += NTHR) {
        float c = lsT[DD * SEGS + s];
        if (c != 0.0f) {
            #pragma unroll
            for (int d = 0; d < DD; ++d)
                unsafeAtomicAdd(&seg_sum[s * DD + d], lsT[d * SEGS + s]);
            unsafeAtomicAdd(&seg_cnt[s], c);
        }
    }
}

__global__ void k_finalize_push(float* __restrict__ ws) {
    const float* seg_sum = ws;
    const float* seg_cnt = ws + 4096;
    float* mus  = ws + 4352;
    float* invw = ws + 8448;
    float* push = ws + 8704;

    __shared__ float muT[DD * SEGS];
    int t = threadIdx.x;  // one seg per thread
    float cnt = seg_cnt[t];
    float ic  = (cnt > 0.0f) ? 1.0f / cnt : 0.0f;
    #pragma unroll
    for (int d = 0; d < DD; ++d) {
        float m = seg_sum[t * DD + d] * ic;
        mus[t * DD + d]   = m;
        muT[d * SEGS + t] = m;
    }
    invw[t] = (cnt > 0.0f) ? 1.0f / ((float)MM * cnt) : 0.0f;
    __syncthreads();

    int b = t >> 5, m1 = t & 31;
    float acc = 0.0f;
    for (int m2 = 0; m2 < MM; ++m2) {
        float pd = 0.0f;
        #pragma unroll
        for (int d = 0; d < DD; ++d)
            pd += fabsf(muT[d * SEGS + b * MM + m1] - muT[d * SEGS + b * MM + m2]);
        float h = 2.0f * DELTA_D - pd;
        if (m2 != m1 && h > 0.0f) acc += h * h;
    }
    float tot = block_reduce_sum(acc);
    if (t == 0) push[0] = tot / (float)(MM * (MM - 1));
}

__global__ void __launch_bounds__(NTHR, 8)
k_pull(const float4* __restrict__ o4,
       const int* __restrict__ labels,
       const int* __restrict__ sub,
       const float* __restrict__ mus,
       const float* __restrict__ invw,
       float* __restrict__ pull_part,
       int n) {
    __shared__ float muL[DD * SEGS];  // seg-major (matches ws mus layout)
    __shared__ float siw[SEGS];
    for (int i = threadIdx.x; i < DD * SEGS; i += NTHR) muL[i] = mus[i];
    for (int i = threadIdx.x; i < SEGS; i += NTHR) siw[i] = invw[i];
    __syncthreads();

    const int tid = threadIdx.x;
    const int j   = tid & 3;
    const int n4  = 4 * n;
    const int qbase = blockIdx.x * (CHUNKP * 4) + tid;

    float4 mreg = {0.0f, 0.0f, 0.0f, 0.0f};
    float iw = 0.0f;
    int cur = -1;
    float acc = 0.0f;

    #pragma unroll 4
    for (int it = 0; it < ITERS; ++it) {
        int q = qbase + it * NTHR;
        bool ok = (q < n4);
        int qc = ok ? q : 0;
        float4 v = o4[qc];                       // coalesced
        int p = qc >> 2;
        int seg = sub[p] * MM + labels[p];
        float ss = v.x*v.x + v.y*v.y + v.z*v.z + v.w*v.w;
        ss += __shfl_xor(ss, 1, 64);
        ss += __shfl_xor(ss, 2, 64);
        float rn = 1.0f / (sqrtf(ss) + NEPS);
        if (seg != cur) {                        // once/thread for canonical
            cur = seg;
            mreg = *(const float4*)&muL[seg * DD + 4 * j];
            iw = siw[seg];
        }
        float d4 = fabsf(mreg.x - v.x * rn) + fabsf(mreg.y - v.y * rn)
                 + fabsf(mreg.z - v.z * rn) + fabsf(mreg.w - v.w * rn);
        d4 += __shfl_xor(d4, 1, 64);
        d4 += __shfl_xor(d4, 2, 64);             // full L1 distance on all lanes
        if (ok && j == 0) {
            float h = d4 - DELTA_V;
            if (h > 0.0f) acc = fmaf(h * h, iw, acc);
        }
    }
    float tot = block_reduce_sum(acc);
    if (threadIdx.x == 0) pull_part[blockIdx.x] = tot;
}

__global__ void k_final(const float* __restrict__ ws, float* __restrict__ out) {
    const float* push      = ws + 8704;
    const float* pull_part = ws + 8720;
    int t = threadIdx.x;
    float v = 0.0f;
    #pragma unroll
    for (int k = 0; k < NBLK / NTHR; ++k) v += pull_part[t + k * NTHR];
    float tot = block_reduce_sum(v);
    if (t == 0) out[0] = (tot + push[0]) * (1.0f / (float)BBATCH);
}

extern "C" void kernel_launch(void* const* d_in, const int* in_sizes, int n_in,
                              void* d_out, int out_size, void* d_ws, size_t ws_size,
                              hipStream_t stream) {
    const float* outputs = (const float*)d_in[0];
    const int* labels    = (const int*)d_in[1];
    const int* sub       = (const int*)d_in[2];
    int n = in_sizes[0] / DD;

    float* ws        = (float*)d_ws;
    float* seg_sum   = ws;
    float* seg_cnt   = ws + 4096;
    float* mus       = ws + 4352;
    float* invw      = ws + 8448;
    float* pull_part = ws + 8720;

    hipMemsetAsync(d_ws, 0, WS_ZERO_FLOATS * sizeof(float), stream);

    k_segsum<<<NBLK, NTHR, 0, stream>>>((const float4*)outputs, labels, sub,
                                        seg_sum, seg_cnt, n);
    k_finalize_push<<<1, NTHR, 0, stream>>>(ws);
    k_pull<<<NBLK, NTHR, 0, stream>>>((const float4*)outputs, labels, sub,
                                      mus, invw, pull_part, n);
    k_final<<<1, NTHR, 0, stream>>>(ws, (float*)d_out);
}